// Round 1
// 296.011 us; speedup vs baseline: 1.1290x; 1.1290x over previous
//
#include <hip/hip_runtime.h>
#include <math.h>

// RelativeAttention: out = round((x_n @ a_n^T)/0.05)*0.05 @ values
//
// Round 18 (from r17 @ 334us): port BOTH GEMMs to the 256^2 8-phase
// counted-vmcnt template (T3+T4) + setprio (T5), on top of the existing
// T1 XCD swizzle + T2 chunk-XOR LDS swizzle (0 bank conflicts measured r17).
//  - 8 waves (2Mx4N), BK=64, 2 K-tiles/group, 8 phases/group.
//  - staging order per K-tile: A-half0, B-half0, B-half1, A-half1;
//    quadrant order (0,0),(0,1),(1,1),(1,0). vmcnt(4) per phase keeps
//    2 half-tiles in flight and guarantees the half-tile consumed next
//    phase has landed (verified phase-by-phase). Epilogue drains 4->2->0.
//  - gemm1 epilogue: quantize + flag lists + swizzled sq flush at 256^2;
//    lists become [64][8192] (same 2MB), fixup re-indexed accordingly.
//  - numerics identical to r17 (f16 chain, same K order, same thresholds;
//    absmax canary 2.685547e-3).
//
// ws layout (bytes):
//   [0x0,       0x24000)   inv_norms f64 (16384 x | 2048 anchors)
//   [0x24000,   0x24200)   counts u32[64] (128 slots reserved)
//   [0x24200,   0x224200)  lists u32[64][8192]
//   [0x324000,  0x2324000) xh f16 [16384][1024] (32MB)
//   [0x2324000, 0x2724000) ah f16 [2048][1024] (4MB)
//   [0x2724000, 0x2B24000) vbT bf16 [1024][2048] (values^T, 4MB)
//   [0x2B24000, 0x6B24000) kb2 bf16 [16384][2048] (2*bin, odd = midpoint)

#define B_ROWS 16384
#define A_ROWS 2048
#define D_DIM  1024
#define H_DIM  1024
#define TILE_CAP 8192u
#define LCAP 2040u

typedef __attribute__((ext_vector_type(8))) short short8;
typedef __attribute__((ext_vector_type(8))) _Float16 half8;
typedef __attribute__((ext_vector_type(4))) float f32x4;

__device__ inline unsigned short bf16_rne(float f) {
  unsigned int u = __float_as_uint(f);
  unsigned int r = (u + 0x7FFFu + ((u >> 16) & 1u)) >> 16;
  return (unsigned short)r;
}
__device__ inline unsigned short f16_bits(float f) {
  _Float16 h = (_Float16)f;
  return __builtin_bit_cast(unsigned short, h);
}
__device__ inline void gload16(const void* g, void* l) {
  __builtin_amdgcn_global_load_lds(
      (const __attribute__((address_space(1))) unsigned int*)g,
      (__attribute__((address_space(3))) unsigned int*)l, 16, 0, 0);
}

template <bool F16>
__device__ __forceinline__ f32x4 mm16(short8 a, short8 b, f32x4 c) {
  if constexpr (F16)
    return __builtin_amdgcn_mfma_f32_16x16x32_f16(
        __builtin_bit_cast(half8, a), __builtin_bit_cast(half8, b), c, 0, 0, 0);
  else
    return __builtin_amdgcn_mfma_f32_16x16x32_bf16(a, b, c, 0, 0, 0);
}

// ------------- fused: norm (f64, r3-proven tree) + f16 convert -------------
__global__ __launch_bounds__(256) void normprep_k(
    const float* __restrict__ src, double* __restrict__ inv_out,
    unsigned short* __restrict__ dst) {
#pragma clang fp contract(off)
  const int r = blockIdx.x;
  const int t = threadIdx.x;
  const float4 v = reinterpret_cast<const float4*>(src + (size_t)r * D_DIM)[t];
  double s = (double)v.x * (double)v.x + (double)v.y * (double)v.y +
             (double)v.z * (double)v.z + (double)v.w * (double)v.w;
#pragma unroll
  for (int off = 32; off > 0; off >>= 1) s += __shfl_down(s, off);
  __shared__ double red[4];
  __shared__ double sinv;
  if ((t & 63) == 0) red[t >> 6] = s;
  __syncthreads();
  if (t == 0) {
    const double n = sqrt(red[0] + red[1] + red[2] + red[3]);
    const double inv = 1.0 / fmax(n, 1e-12);
    inv_out[r] = inv;
    sinv = inv;
  }
  __syncthreads();
  const float invn = (float)sinv;
  ushort4 o;
  o.x = f16_bits(v.x * invn); o.y = f16_bits(v.y * invn);
  o.z = f16_bits(v.z * invn); o.w = f16_bits(v.w * invn);
  reinterpret_cast<ushort4*>(dst + (size_t)r * D_DIM)[t] = o;
}

// ---------------------- prep: values^T as bf16 (+ zero counts) -------------
__global__ void prep_vt_k(const float* __restrict__ values,
                          unsigned short* __restrict__ vbT,
                          unsigned int* __restrict__ counts) {
  __shared__ float s[16][17];
  const int tx = threadIdx.x, ty = threadIdx.y;
  if (blockIdx.x == 0 && blockIdx.y == 0) {
    const int ft = ty * 16 + tx;
    if (ft < 128) counts[ft] = 0;
  }
  const int h0 = blockIdx.x * 16, a0 = blockIdx.y * 16;
  s[ty][tx] = values[(size_t)(a0 + ty) * H_DIM + h0 + tx];
  __syncthreads();
  vbT[(size_t)(h0 + ty) * A_ROWS + a0 + tx] = bf16_rne(s[tx][ty]);
}

// ------ 256x256 / BK=64 / 8-wave / 8-phase counted-vmcnt GEMM core --------
// LDS: buf0 {A:[256][64] @0, B @16384}, buf1 {A @32768, B @49152} (shorts).
// Chunk-XOR swizzle: row r's chunk k (16B) lives at slot k^(r&7); staging
// pre-swizzles the per-lane GLOBAL source so the LDS dest stays linear.
#define GBAR() __builtin_amdgcn_s_barrier()
#define GLGKM0() do { asm volatile("s_waitcnt lgkmcnt(0)" ::: "memory"); \
                      __builtin_amdgcn_sched_barrier(0); } while (0)
#define GVMC(n) asm volatile("s_waitcnt vmcnt(" #n ")" ::: "memory")

#define SCA(buf, c, kv) gload16(aS + (size_t)(c) * 64 * KDIM + (kv), \
                                (buf) + (c) * 4096 + tid * 8)
#define SCB(buf, c, kv) gload16(bS + (size_t)(c) * 64 * KDIM + (kv), \
                                (buf) + (c) * 4096 + tid * 8)

#define LDX(mh, buf) do { \
    _Pragma("unroll") for (int ki_ = 0; ki_ < 2; ++ki_) \
    _Pragma("unroll") for (int m_ = 0; m_ < 4; ++m_) { \
      const int r_ = (mh) * 128 + wr * 64 + m_ * 16 + cl; \
      const int cc_ = (ki_ * 4 + kg) ^ (r_ & 7); \
      Xf[ki_][m_] = *reinterpret_cast<const short8*>((buf) + r_ * 64 + cc_ * 8); \
    } } while (0)

#define LDB(nh, buf) do { \
    _Pragma("unroll") for (int ki_ = 0; ki_ < 2; ++ki_) \
    _Pragma("unroll") for (int n_ = 0; n_ < 2; ++n_) { \
      const int r_ = (nh) * 128 + wc * 32 + n_ * 16 + cl; \
      const int cc_ = (ki_ * 4 + kg) ^ (r_ & 7); \
      Bf[nh][ki_][n_] = *reinterpret_cast<const short8*>((buf) + r_ * 64 + cc_ * 8); \
    } } while (0)

#define MM4(mh, nh) do { \
    __builtin_amdgcn_s_setprio(1); \
    _Pragma("unroll") for (int ki_ = 0; ki_ < 2; ++ki_) \
    _Pragma("unroll") for (int m_ = 0; m_ < 4; ++m_) \
    _Pragma("unroll") for (int n_ = 0; n_ < 2; ++n_) \
      acc[(mh) * 4 + m_][(nh) * 2 + n_] = mm16<F16>( \
          Xf[ki_][m_], Bf[nh][ki_][n_], acc[(mh) * 4 + m_][(nh) * 2 + n_]); \
    __builtin_amdgcn_s_setprio(0); \
  } while (0)

template <int KDIM, bool F16>
__device__ __forceinline__ void gemm_core(
    const unsigned short* __restrict__ Amat, int m0,
    const unsigned short* __restrict__ Bmat, int n0,
    unsigned short* smem, f32x4 (&acc)[8][4], const int tid) {
  static_assert(KDIM % 128 == 0, "KDIM must be a multiple of 128");
  const int lane = tid & 63, w = tid >> 6;
  const int wr = w >> 2, wc = w & 3;
  const int cl = lane & 15, kg = lane >> 4;
  unsigned short* const A0b = smem;
  unsigned short* const B0b = smem + 16384;
  unsigned short* const A1b = smem + 32768;
  unsigned short* const B1b = smem + 49152;
  // staging geometry: call c covers rows c*64 + (tid>>3), chunk slot tid&7;
  // source chunk = slot ^ (row&7); (c*64)&7==0 so the XOR is c-invariant.
  const int srow = tid >> 3;
  const int tcs = (tid & 7) ^ (srow & 7);
  const unsigned short* aS = Amat + (size_t)(m0 + srow) * KDIM + tcs * 8;
  const unsigned short* bS = Bmat + (size_t)(n0 + srow) * KDIM + tcs * 8;

  short8 Xf[2][4], Bf[2][2][2];

  // prologue: K-tile 0 into buf0, half-tile order A0,B0,B1,A1
  SCA(A0b, 0, 0); SCA(A0b, 1, 0);
  SCB(B0b, 0, 0); SCB(B0b, 1, 0);
  SCB(B0b, 2, 0); SCB(B0b, 3, 0);
  SCA(A0b, 2, 0); SCA(A0b, 3, 0);
  GVMC(4);   // A-half0 + B-half0 of tile 0 landed
  GBAR();

  constexpr int G = KDIM / 128;  // groups of 2 K-tiles
#pragma unroll 1
  for (int g = 0; g < G - 1; ++g) {
    const int kA = g * 128 + 64;   // odd tile -> buf1, staged ph1-4
    const int kB = g * 128 + 128;  // next even tile -> buf0, staged ph5-8
    // ph1: quad(0,0) from buf0
    LDX(0, A0b); LDB(0, B0b);
    SCA(A1b, 0, kA); SCA(A1b, 1, kA);
    GBAR(); GLGKM0(); MM4(0, 0); GVMC(4); GBAR();
    // ph2: quad(0,1)
    LDB(1, B0b);
    SCB(B1b, 0, kA); SCB(B1b, 1, kA);
    GBAR(); GLGKM0(); MM4(0, 1); GVMC(4); GBAR();
    // ph3: quad(1,1)
    LDX(1, A0b);
    SCB(B1b, 2, kA); SCB(B1b, 3, kA);
    GBAR(); GLGKM0(); MM4(1, 1); GVMC(4); GBAR();
    // ph4: quad(1,0) -- Bf[0] still live
    SCA(A1b, 2, kA); SCA(A1b, 3, kA);
    GBAR(); MM4(1, 0); GVMC(4); GBAR();
    // ph5: quad(0,0) from buf1
    LDX(0, A1b); LDB(0, B1b);
    SCA(A0b, 0, kB); SCA(A0b, 1, kB);
    GBAR(); GLGKM0(); MM4(0, 0); GVMC(4); GBAR();
    // ph6
    LDB(1, B1b);
    SCB(B0b, 0, kB); SCB(B0b, 1, kB);
    GBAR(); GLGKM0(); MM4(0, 1); GVMC(4); GBAR();
    // ph7
    LDX(1, A1b);
    SCB(B0b, 2, kB); SCB(B0b, 3, kB);
    GBAR(); GLGKM0(); MM4(1, 1); GVMC(4); GBAR();
    // ph8
    SCA(A0b, 2, kB); SCA(A0b, 3, kB);
    GBAR(); MM4(1, 0); GVMC(4); GBAR();
  }
  // final group: tiles KDIM-128 (buf0) and KDIM-64 (buf1, staged ph1-4)
  {
    const int kA = KDIM - 64;
    LDX(0, A0b); LDB(0, B0b);
    SCA(A1b, 0, kA); SCA(A1b, 1, kA);
    GBAR(); GLGKM0(); MM4(0, 0); GVMC(4); GBAR();
    LDB(1, B0b);
    SCB(B1b, 0, kA); SCB(B1b, 1, kA);
    GBAR(); GLGKM0(); MM4(0, 1); GVMC(4); GBAR();
    LDX(1, A0b);
    SCB(B1b, 2, kA); SCB(B1b, 3, kA);
    GBAR(); GLGKM0(); MM4(1, 1); GVMC(4); GBAR();
    SCA(A1b, 2, kA); SCA(A1b, 3, kA);
    GBAR(); MM4(1, 0); GVMC(4); GBAR();
    // drain phases: no staging; 4 -> 2 -> 0
    LDX(0, A1b); LDB(0, B1b);
    GBAR(); GLGKM0(); MM4(0, 0); GVMC(2); GBAR();
    LDB(1, B1b);
    GBAR(); GLGKM0(); MM4(0, 1); GVMC(0); GBAR();
    LDX(1, A1b);
    GBAR(); GLGKM0(); MM4(1, 1); GBAR();
    MM4(1, 0);
  }
}

// ---- GEMM1: f16 chain, 256^2 8-phase core + quantize/flag/flush epilogue --
__global__ __launch_bounds__(512, 2) void gemm1_k(
    const unsigned short* __restrict__ xh, const unsigned short* __restrict__ ah,
    unsigned short* __restrict__ kb2, unsigned int* __restrict__ counts,
    unsigned int* __restrict__ lists) {
  __shared__ __align__(16) unsigned short smem[65536];  // 128 KB
  __shared__ unsigned int lmeta[2050];

  const int tid = threadIdx.x, lane = tid & 63, w = tid >> 6;
  const int wr = w >> 2, wc = w & 3;
  const int cl = lane & 15, kg = lane >> 4;
  // XCD-bijective swizzle (m204; nwg=512, nwg%8==0, q=64)
  const int orig = blockIdx.y * 8 + blockIdx.x;
  const int swz = (orig & 7) * 64 + (orig >> 3);
  const int m0 = (swz >> 3) * 256, n0 = (swz & 7) * 256;
  const int bt = m0 >> 8;  // 256-row slab index 0..63

  f32x4 acc[8][4];
#pragma unroll
  for (int m = 0; m < 8; ++m)
#pragma unroll
    for (int n = 0; n < 4; ++n)
#pragma unroll
      for (int q = 0; q < 4; ++q) acc[m][n][q] = 0.0f;

  if (tid == 0) lmeta[0] = 0;  // published by core's prologue barrier

  gemm_core<D_DIM, true>(xh, m0, ah, n0, smem, acc, tid);

  // ---- epilogue: quantize -> bf16 2k in LDS (XOR-swz), flags, flush ------
  __syncthreads();
  unsigned short* sq = smem;  // [256][256] bf16, chunk-swizzled
  unsigned int* mylist = lists + (size_t)bt * TILE_CAP;
#pragma unroll
  for (int mi = 0; mi < 8; ++mi)
#pragma unroll
    for (int ni = 0; ni < 4; ++ni) {
      const int rowb = (mi >> 2) * 128 + wr * 64 + (mi & 3) * 16 + kg * 4;
      const int col = (ni >> 1) * 128 + wc * 32 + (ni & 1) * 16 + cl;
#pragma unroll
      for (int reg = 0; reg < 4; ++reg) {
        const int row = rowb + reg;
        const float kr = acc[mi][ni][reg] * 20.0f;
        const float rr = rintf(kr);
        if (0.5f - fabsf(kr - rr) < 2e-3f) {  // r7-r17-validated window
          const unsigned int code =
              ((unsigned int)(m0 + row) << 11) | (unsigned int)(n0 + col);
          const unsigned int li = atomicAdd(&lmeta[0], 1u);  // LDS atomic
          if (li < LCAP) lmeta[1 + li] = code;
          else {
            const unsigned int gi = atomicAdd(&counts[bt], 1u);
            if (gi < TILE_CAP) mylist[gi] = code;
          }
        }
        // swizzled store: chunk (col>>3) with low 3 bits XOR (row&7)
        const int ch = col >> 3;
        const int csw = (ch & 24) | ((ch & 7) ^ (row & 7));
        sq[row * 256 + csw * 8 + (col & 7)] =
            bf16_rne((float)(2 * (int)rr));  // exact
      }
    }
  __syncthreads();
  if (tid == 0) {
    const unsigned int c = lmeta[0] < LCAP ? lmeta[0] : LCAP;
    lmeta[2049] = atomicAdd(&counts[bt], c);  // ONE global atomic per block
  }
  __syncthreads();
  {
    const unsigned int c = lmeta[0] < LCAP ? lmeta[0] : LCAP;
    const unsigned int base = lmeta[2049];
    for (unsigned int t = tid; t < c; t += 512)
      if (base + t < TILE_CAP) mylist[base + t] = lmeta[1 + t];
  }
  {
    const int row = tid >> 1, half = tid & 1;
    unsigned short* dst = kb2 + (size_t)(m0 + row) * A_ROWS + n0 + half * 128;
#pragma unroll
    for (int j = 0; j < 16; ++j) {
      const int creal = half * 16 + j;
      const int csw = (creal & 24) | ((creal & 7) ^ (row & 7));
      reinterpret_cast<int4*>(dst)[j] =
          *reinterpret_cast<const int4*>(sq + row * 256 + csw * 8);
    }
  }
}

// ---- fixup: 4 flags/wave (16-lane groups), bucketed, XCD-co-located -------
__global__ __launch_bounds__(256) void fixup_k(
    const float* __restrict__ x, const float* __restrict__ anc,
    const double* __restrict__ inv_norms, const unsigned int* __restrict__ counts,
    const unsigned int* __restrict__ lists, unsigned short* __restrict__ kb2) {
  const int bt = blockIdx.x & 63;
  const int sub = blockIdx.x >> 6;          // 0..31
  unsigned int cnt = counts[bt];
  if (cnt > TILE_CAP) cnt = TILE_CAP;
  const unsigned int* mylist = lists + (size_t)bt * TILE_CAP;
  const int lane = threadIdx.x & 63;
  const int wib = threadIdx.x >> 6;         // wave in block 0..3
  const int g = lane >> 4;                  // flag group 0..3
  const int l16 = lane & 15;
  for (unsigned int i = (unsigned int)((sub * 4 + wib) * 4 + g); i < cnt; i += 512) {
    const unsigned int code = mylist[i];
    const int b = code >> 11, a = code & 2047;
    const float4* xp = reinterpret_cast<const float4*>(x + (size_t)b * D_DIM) + l16;
    const float4* ap = reinterpret_cast<const float4*>(anc + (size_t)a * D_DIM) + l16;
    double part[4] = {0.0, 0.0, 0.0, 0.0};
#pragma unroll
    for (int q = 0; q < 16; ++q) {
      const float4 xv = xp[16 * q];
      const float4 av = ap[16 * q];
      part[q & 3] += (double)xv.x * (double)av.x + (double)xv.y * (double)av.y +
                     (double)xv.z * (double)av.z + (double)xv.w * (double)av.w;
    }
    double s = (part[0] + part[1]) + (part[2] + part[3]);
    s += __shfl_xor(s, 8);
    s += __shfl_xor(s, 4);
    s += __shfl_xor(s, 2);
    s += __shfl_xor(s, 1);
    if (l16 == 0) {
      const double sim = s * inv_norms[b] * inv_norms[B_ROWS + a];
      const double kr = sim / 0.05;
      const double r = rint(kr);
      const double fr = kr - r;
      int k2 = 2 * (int)r;
      if (0.5 - fabs(fr) < 2.5e-6) k2 += (fr > 0.0) ? 1 : -1;  // midpoint hedge
      kb2[(size_t)b * A_ROWS + a] = bf16_rne((float)k2);       // exact int
    }
  }
}

// ---- GEMM2: bf16 chain, K=2048, 256^2 8-phase core, out = .025*k2@vbT -----
__global__ __launch_bounds__(512, 2) void gemm2_k(
    const unsigned short* __restrict__ kb2, const unsigned short* __restrict__ vbT,
    float* __restrict__ out) {
  __shared__ __align__(16) unsigned short smem[65536];  // 128 KB

  const int tid = threadIdx.x, lane = tid & 63, w = tid >> 6;
  const int wr = w >> 2, wc = w & 3;
  const int cl = lane & 15, kg = lane >> 4;
  // XCD-bijective swizzle (nwg=256, q=32)
  const int orig = blockIdx.y * 4 + blockIdx.x;
  const int swz = (orig & 7) * 32 + (orig >> 3);
  const int m0 = (swz >> 2) * 256, h0 = (swz & 3) * 256;

  f32x4 acc[8][4];
#pragma unroll
  for (int m = 0; m < 8; ++m)
#pragma unroll
    for (int n = 0; n < 4; ++n)
#pragma unroll
      for (int q = 0; q < 4; ++q) acc[m][n][q] = 0.0f;

  gemm_core<A_ROWS, false>(kb2, m0, vbT, h0, smem, acc, tid);

#pragma unroll
  for (int mi = 0; mi < 8; ++mi)
#pragma unroll
    for (int ni = 0; ni < 4; ++ni) {
      const int rowb = (mi >> 2) * 128 + wr * 64 + (mi & 3) * 16 + kg * 4;
      const int col = (ni >> 1) * 128 + wc * 32 + (ni & 1) * 16 + cl;
#pragma unroll
      for (int reg = 0; reg < 4; ++reg)
        out[(size_t)(m0 + rowb + reg) * H_DIM + h0 + col] =
            0.025f * acc[mi][ni][reg];
    }
}

// ---------------------------------------------------------------------------
extern "C" void kernel_launch(void* const* d_in, const int* in_sizes, int n_in,
                              void* d_out, int out_size, void* d_ws, size_t ws_size,
                              hipStream_t stream) {
  const float* x      = (const float*)d_in[0];
  const float* anc    = (const float*)d_in[1];
  const float* values = (const float*)d_in[2];
  float* out = (float*)d_out;

  char* ws = (char*)d_ws;
  double* inv_norms    = (double*)(ws);
  unsigned int* counts = (unsigned int*)(ws + 0x24000);
  unsigned int* lists  = (unsigned int*)(ws + 0x24200);
  unsigned short* xh   = (unsigned short*)(ws + 0x324000);
  unsigned short* ah   = (unsigned short*)(ws + 0x2324000);
  unsigned short* vbT  = (unsigned short*)(ws + 0x2724000);
  unsigned short* kb2  = (unsigned short*)(ws + 0x2B24000);

  normprep_k<<<B_ROWS, 256, 0, stream>>>(x, inv_norms, xh);
  normprep_k<<<A_ROWS, 256, 0, stream>>>(anc, inv_norms + B_ROWS, ah);
  prep_vt_k<<<dim3(H_DIM / 16, A_ROWS / 16), dim3(16, 16), 0, stream>>>(values, vbT, counts);
  gemm1_k<<<dim3(A_ROWS / 256, B_ROWS / 256), 512, 0, stream>>>(xh, ah, kb2, counts, lists);
  fixup_k<<<2048, 256, 0, stream>>>(x, anc, inv_norms, counts, lists, kb2);
  gemm2_k<<<dim3(H_DIM / 256, B_ROWS / 256), 512, 0, stream>>>(kb2, vbT, out);
}

// Round 2
// 295.494 us; speedup vs baseline: 1.1310x; 1.0017x over previous
//
#include <hip/hip_runtime.h>
#include <math.h>

// RelativeAttention: out = round((x_n @ a_n^T)/0.05)*0.05 @ values
//
// Round 19 (from r18 @ 296us): faithful m201/T4 wait schedule in gemm_core.
//  - r18 waited vmcnt(4) EVERY phase with only 2 half-tiles ahead (stage->
//    consume gap 2-3 phases < load latency). Now: stage 1 half/phase shifted
//    3 halves ahead (tile t's halves land at phases 4t-6..4t-3), waits ONLY
//    at ph4/ph8 with vmcnt(6) ("all but the 3 newest halves landed" = next
//    tile fully resident). Slot-liveness verified: each stage lands at/after
//    its slot's last read (A-h0 freed ph2, B-h0 ph2, B-h1 ph3, A-h1 ph4),
//    ordered by the phase closing barrier. Prologue stages 7 halves then
//    vmcnt(6); tail group drains with one vmcnt(0) at ph4.
//  - + template's lgkmcnt(8) hint before barrier on 12-ds_read phases.
//  - epilogue/fixup/numerics identical to r18 (absmax canary 2.685547e-3).
//
// ws layout (bytes):
//   [0x0,       0x24000)   inv_norms f64 (16384 x | 2048 anchors)
//   [0x24000,   0x24200)   counts u32[64] (128 slots reserved)
//   [0x24200,   0x224200)  lists u32[64][8192]
//   [0x324000,  0x2324000) xh f16 [16384][1024] (32MB)
//   [0x2324000, 0x2724000) ah f16 [2048][1024] (4MB)
//   [0x2724000, 0x2B24000) vbT bf16 [1024][2048] (values^T, 4MB)
//   [0x2B24000, 0x6B24000) kb2 bf16 [16384][2048] (2*bin, odd = midpoint)

#define B_ROWS 16384
#define A_ROWS 2048
#define D_DIM  1024
#define H_DIM  1024
#define TILE_CAP 8192u
#define LCAP 2040u

typedef __attribute__((ext_vector_type(8))) short short8;
typedef __attribute__((ext_vector_type(8))) _Float16 half8;
typedef __attribute__((ext_vector_type(4))) float f32x4;

__device__ inline unsigned short bf16_rne(float f) {
  unsigned int u = __float_as_uint(f);
  unsigned int r = (u + 0x7FFFu + ((u >> 16) & 1u)) >> 16;
  return (unsigned short)r;
}
__device__ inline unsigned short f16_bits(float f) {
  _Float16 h = (_Float16)f;
  return __builtin_bit_cast(unsigned short, h);
}
__device__ inline void gload16(const void* g, void* l) {
  __builtin_amdgcn_global_load_lds(
      (const __attribute__((address_space(1))) unsigned int*)g,
      (__attribute__((address_space(3))) unsigned int*)l, 16, 0, 0);
}

template <bool F16>
__device__ __forceinline__ f32x4 mm16(short8 a, short8 b, f32x4 c) {
  if constexpr (F16)
    return __builtin_amdgcn_mfma_f32_16x16x32_f16(
        __builtin_bit_cast(half8, a), __builtin_bit_cast(half8, b), c, 0, 0, 0);
  else
    return __builtin_amdgcn_mfma_f32_16x16x32_bf16(a, b, c, 0, 0, 0);
}

// ------------- fused: norm (f64, r3-proven tree) + f16 convert -------------
__global__ __launch_bounds__(256) void normprep_k(
    const float* __restrict__ src, double* __restrict__ inv_out,
    unsigned short* __restrict__ dst) {
#pragma clang fp contract(off)
  const int r = blockIdx.x;
  const int t = threadIdx.x;
  const float4 v = reinterpret_cast<const float4*>(src + (size_t)r * D_DIM)[t];
  double s = (double)v.x * (double)v.x + (double)v.y * (double)v.y +
             (double)v.z * (double)v.z + (double)v.w * (double)v.w;
#pragma unroll
  for (int off = 32; off > 0; off >>= 1) s += __shfl_down(s, off);
  __shared__ double red[4];
  __shared__ double sinv;
  if ((t & 63) == 0) red[t >> 6] = s;
  __syncthreads();
  if (t == 0) {
    const double n = sqrt(red[0] + red[1] + red[2] + red[3]);
    const double inv = 1.0 / fmax(n, 1e-12);
    inv_out[r] = inv;
    sinv = inv;
  }
  __syncthreads();
  const float invn = (float)sinv;
  ushort4 o;
  o.x = f16_bits(v.x * invn); o.y = f16_bits(v.y * invn);
  o.z = f16_bits(v.z * invn); o.w = f16_bits(v.w * invn);
  reinterpret_cast<ushort4*>(dst + (size_t)r * D_DIM)[t] = o;
}

// ---------------------- prep: values^T as bf16 (+ zero counts) -------------
__global__ void prep_vt_k(const float* __restrict__ values,
                          unsigned short* __restrict__ vbT,
                          unsigned int* __restrict__ counts) {
  __shared__ float s[16][17];
  const int tx = threadIdx.x, ty = threadIdx.y;
  if (blockIdx.x == 0 && blockIdx.y == 0) {
    const int ft = ty * 16 + tx;
    if (ft < 128) counts[ft] = 0;
  }
  const int h0 = blockIdx.x * 16, a0 = blockIdx.y * 16;
  s[ty][tx] = values[(size_t)(a0 + ty) * H_DIM + h0 + tx];
  __syncthreads();
  vbT[(size_t)(h0 + ty) * A_ROWS + a0 + tx] = bf16_rne(s[tx][ty]);
}

// ------ 256x256 / BK=64 / 8-wave / 8-phase counted-vmcnt GEMM core --------
// LDS: buf0 {A:[256][64] @0, B @16384}, buf1 {A @32768, B @49152} (shorts).
// Chunk-XOR swizzle: row r's chunk k (16B) lives at slot k^(r&7); staging
// pre-swizzles the per-lane GLOBAL source so the LDS dest stays linear.
#define GBAR() __builtin_amdgcn_s_barrier()
#define GLGKM0() do { asm volatile("s_waitcnt lgkmcnt(0)" ::: "memory"); \
                      __builtin_amdgcn_sched_barrier(0); } while (0)
#define GVMC(n) asm volatile("s_waitcnt vmcnt(" #n ")" ::: "memory")
#define GLKH() asm volatile("s_waitcnt lgkmcnt(8)" ::: "memory")

#define SCA(buf, c, kv) gload16(aS + (size_t)(c) * 64 * KDIM + (kv), \
                                (buf) + (c) * 4096 + tid * 8)
#define SCB(buf, c, kv) gload16(bS + (size_t)(c) * 64 * KDIM + (kv), \
                                (buf) + (c) * 4096 + tid * 8)

#define LDX(mh, buf) do { \
    _Pragma("unroll") for (int ki_ = 0; ki_ < 2; ++ki_) \
    _Pragma("unroll") for (int m_ = 0; m_ < 4; ++m_) { \
      const int r_ = (mh) * 128 + wr * 64 + m_ * 16 + cl; \
      const int cc_ = (ki_ * 4 + kg) ^ (r_ & 7); \
      Xf[ki_][m_] = *reinterpret_cast<const short8*>((buf) + r_ * 64 + cc_ * 8); \
    } } while (0)

#define LDB(nh, buf) do { \
    _Pragma("unroll") for (int ki_ = 0; ki_ < 2; ++ki_) \
    _Pragma("unroll") for (int n_ = 0; n_ < 2; ++n_) { \
      const int r_ = (nh) * 128 + wc * 32 + n_ * 16 + cl; \
      const int cc_ = (ki_ * 4 + kg) ^ (r_ & 7); \
      Bf[nh][ki_][n_] = *reinterpret_cast<const short8*>((buf) + r_ * 64 + cc_ * 8); \
    } } while (0)

#define MM4(mh, nh) do { \
    __builtin_amdgcn_s_setprio(1); \
    _Pragma("unroll") for (int ki_ = 0; ki_ < 2; ++ki_) \
    _Pragma("unroll") for (int m_ = 0; m_ < 4; ++m_) \
    _Pragma("unroll") for (int n_ = 0; n_ < 2; ++n_) \
      acc[(mh) * 4 + m_][(nh) * 2 + n_] = mm16<F16>( \
          Xf[ki_][m_], Bf[nh][ki_][n_], acc[(mh) * 4 + m_][(nh) * 2 + n_]); \
    __builtin_amdgcn_s_setprio(0); \
  } while (0)

template <int KDIM, bool F16>
__device__ __forceinline__ void gemm_core(
    const unsigned short* __restrict__ Amat, int m0,
    const unsigned short* __restrict__ Bmat, int n0,
    unsigned short* smem, f32x4 (&acc)[8][4], const int tid) {
  static_assert(KDIM % 128 == 0 && KDIM >= 256, "KDIM");
  const int lane = tid & 63, w = tid >> 6;
  const int wr = w >> 2, wc = w & 3;
  const int cl = lane & 15, kg = lane >> 4;
  unsigned short* const A0b = smem;
  unsigned short* const B0b = smem + 16384;
  unsigned short* const A1b = smem + 32768;
  unsigned short* const B1b = smem + 49152;
  // staging geometry: call c covers rows c*64 + (tid>>3), chunk slot tid&7;
  // source chunk = slot ^ (row&7); (c*64)&7==0 so the XOR is c-invariant.
  const int srow = tid >> 3;
  const int tcs = (tid & 7) ^ (srow & 7);
  const unsigned short* aS = Amat + (size_t)(m0 + srow) * KDIM + tcs * 8;
  const unsigned short* bS = Bmat + (size_t)(n0 + srow) * KDIM + tcs * 8;

  short8 Xf[2][4], Bf[2][2][2];

  // prologue: tile0 (4 halves) + tile1 (3 halves) = 14 loads; wait all but
  // the 3 newest halves -> tile0 resident, 3 halves in flight (steady state).
  SCA(A0b, 0, 0); SCA(A0b, 1, 0);
  SCB(B0b, 0, 0); SCB(B0b, 1, 0);
  SCB(B0b, 2, 0); SCB(B0b, 3, 0);
  SCA(A0b, 2, 0); SCA(A0b, 3, 0);
  SCA(A1b, 0, 64); SCA(A1b, 1, 64);
  SCB(B1b, 0, 64); SCB(B1b, 1, 64);
  SCB(B1b, 2, 64); SCB(B1b, 3, 64);
  GVMC(6);
  GBAR();

  constexpr int G = KDIM / 128;  // groups of 2 K-tiles
#pragma unroll 1
  for (int g = 0; g < G - 1; ++g) {
    const int kA = g * 128 + 64;   // t1 = 2g+1 (buf1): its A-h1, staged ph1
    const int kB = g * 128 + 128;  // t2 = 2g+2 (buf0): staged ph2-5
    const int kC = g * 128 + 192;  // t3 = 2g+3 (buf1): halves 0-2, ph6-8
    // ph1: quad(0,0) from buf0; stage A1-h1 (t1, read ph7)
    LDX(0, A0b); LDB(0, B0b);
    SCA(A1b, 2, kA); SCA(A1b, 3, kA);
    GLKH(); GBAR(); GLGKM0(); MM4(0, 0); GBAR();
    // ph2: quad(0,1); stage A0-h0 (t2) [t0 A-h0 last read ph1]
    LDB(1, B0b);
    SCA(A0b, 0, kB); SCA(A0b, 1, kB);
    GBAR(); GLGKM0(); MM4(0, 1); GBAR();
    // ph3: quad(1,1); stage B0-h0 (t2) [t0 B-h0 last read ph1]
    LDX(1, A0b);
    SCB(B0b, 0, kB); SCB(B0b, 1, kB);
    GBAR(); GLGKM0(); MM4(1, 1); GBAR();
    // ph4: quad(1,0); stage B0-h1 (t2) [t0 B-h1 last read ph2];
    // vmcnt(6): all but {ph2,ph3,ph4} halves landed -> t1 fully resident.
    SCB(B0b, 2, kB); SCB(B0b, 3, kB);
    GBAR(); MM4(1, 0); GVMC(6); GBAR();
    // ph5: quad(0,0) from buf1; stage A0-h1 (t2) [t0 A-h1 last read ph3]
    LDX(0, A1b); LDB(0, B1b);
    SCA(A0b, 2, kB); SCA(A0b, 3, kB);
    GLKH(); GBAR(); GLGKM0(); MM4(0, 0); GBAR();
    // ph6: quad(0,1); stage A1-h0 (t3) [t1 A-h0 last read ph5]
    LDB(1, B1b);
    SCA(A1b, 0, kC); SCA(A1b, 1, kC);
    GBAR(); GLGKM0(); MM4(0, 1); GBAR();
    // ph7: quad(1,1); stage B1-h0 (t3) [t1 B-h0 last read ph5]
    LDX(1, A1b);
    SCB(B1b, 0, kC); SCB(B1b, 1, kC);
    GBAR(); GLGKM0(); MM4(1, 1); GBAR();
    // ph8: quad(1,0); stage B1-h1 (t3) [t1 B-h1 last read ph6];
    // vmcnt(6): all but {ph6,ph7,ph8} halves landed -> t2 fully resident.
    SCB(B1b, 2, kC); SCB(B1b, 3, kC);
    GBAR(); MM4(1, 0); GVMC(6); GBAR();
  }
  // tail group (g = G-1): only t1's A-h1 left to stage; drain at ph4.
  {
    const int kA = KDIM - 64;
    LDX(0, A0b); LDB(0, B0b);
    SCA(A1b, 2, kA); SCA(A1b, 3, kA);
    GLKH(); GBAR(); GLGKM0(); MM4(0, 0); GBAR();
    LDB(1, B0b);
    GBAR(); GLGKM0(); MM4(0, 1); GBAR();
    LDX(1, A0b);
    GBAR(); GLGKM0(); MM4(1, 1); GBAR();
    GBAR(); MM4(1, 0); GVMC(0); GBAR();
    LDX(0, A1b); LDB(0, B1b);
    GBAR(); GLGKM0(); MM4(0, 0); GBAR();
    LDB(1, B1b);
    GBAR(); GLGKM0(); MM4(0, 1); GBAR();
    LDX(1, A1b);
    GBAR(); GLGKM0(); MM4(1, 1); GBAR();
    MM4(1, 0);
  }
}

// ---- GEMM1: f16 chain, 256^2 8-phase core + quantize/flag/flush epilogue --
__global__ __launch_bounds__(512, 2) void gemm1_k(
    const unsigned short* __restrict__ xh, const unsigned short* __restrict__ ah,
    unsigned short* __restrict__ kb2, unsigned int* __restrict__ counts,
    unsigned int* __restrict__ lists) {
  __shared__ __align__(16) unsigned short smem[65536];  // 128 KB
  __shared__ unsigned int lmeta[2050];

  const int tid = threadIdx.x, lane = tid & 63, w = tid >> 6;
  const int wr = w >> 2, wc = w & 3;
  const int cl = lane & 15, kg = lane >> 4;
  // XCD-bijective swizzle (m204; nwg=512, nwg%8==0, q=64)
  const int orig = blockIdx.y * 8 + blockIdx.x;
  const int swz = (orig & 7) * 64 + (orig >> 3);
  const int m0 = (swz >> 3) * 256, n0 = (swz & 7) * 256;
  const int bt = m0 >> 8;  // 256-row slab index 0..63

  f32x4 acc[8][4];
#pragma unroll
  for (int m = 0; m < 8; ++m)
#pragma unroll
    for (int n = 0; n < 4; ++n)
#pragma unroll
      for (int q = 0; q < 4; ++q) acc[m][n][q] = 0.0f;

  if (tid == 0) lmeta[0] = 0;  // published by core's prologue barrier

  gemm_core<D_DIM, true>(xh, m0, ah, n0, smem, acc, tid);

  // ---- epilogue: quantize -> bf16 2k in LDS (XOR-swz), flags, flush ------
  __syncthreads();
  unsigned short* sq = smem;  // [256][256] bf16, chunk-swizzled
  unsigned int* mylist = lists + (size_t)bt * TILE_CAP;
#pragma unroll
  for (int mi = 0; mi < 8; ++mi)
#pragma unroll
    for (int ni = 0; ni < 4; ++ni) {
      const int rowb = (mi >> 2) * 128 + wr * 64 + (mi & 3) * 16 + kg * 4;
      const int col = (ni >> 1) * 128 + wc * 32 + (ni & 1) * 16 + cl;
#pragma unroll
      for (int reg = 0; reg < 4; ++reg) {
        const int row = rowb + reg;
        const float kr = acc[mi][ni][reg] * 20.0f;
        const float rr = rintf(kr);
        if (0.5f - fabsf(kr - rr) < 2e-3f) {  // r7-r18-validated window
          const unsigned int code =
              ((unsigned int)(m0 + row) << 11) | (unsigned int)(n0 + col);
          const unsigned int li = atomicAdd(&lmeta[0], 1u);  // LDS atomic
          if (li < LCAP) lmeta[1 + li] = code;
          else {
            const unsigned int gi = atomicAdd(&counts[bt], 1u);
            if (gi < TILE_CAP) mylist[gi] = code;
          }
        }
        // swizzled store: chunk (col>>3) with low 3 bits XOR (row&7)
        const int ch = col >> 3;
        const int csw = (ch & 24) | ((ch & 7) ^ (row & 7));
        sq[row * 256 + csw * 8 + (col & 7)] =
            bf16_rne((float)(2 * (int)rr));  // exact
      }
    }
  __syncthreads();
  if (tid == 0) {
    const unsigned int c = lmeta[0] < LCAP ? lmeta[0] : LCAP;
    lmeta[2049] = atomicAdd(&counts[bt], c);  // ONE global atomic per block
  }
  __syncthreads();
  {
    const unsigned int c = lmeta[0] < LCAP ? lmeta[0] : LCAP;
    const unsigned int base = lmeta[2049];
    for (unsigned int t = tid; t < c; t += 512)
      if (base + t < TILE_CAP) mylist[base + t] = lmeta[1 + t];
  }
  {
    const int row = tid >> 1, half = tid & 1;
    unsigned short* dst = kb2 + (size_t)(m0 + row) * A_ROWS + n0 + half * 128;
#pragma unroll
    for (int j = 0; j < 16; ++j) {
      const int creal = half * 16 + j;
      const int csw = (creal & 24) | ((creal & 7) ^ (row & 7));
      reinterpret_cast<int4*>(dst)[j] =
          *reinterpret_cast<const int4*>(sq + row * 256 + csw * 8);
    }
  }
}

// ---- fixup: 4 flags/wave (16-lane groups), bucketed, XCD-co-located -------
__global__ __launch_bounds__(256) void fixup_k(
    const float* __restrict__ x, const float* __restrict__ anc,
    const double* __restrict__ inv_norms, const unsigned int* __restrict__ counts,
    const unsigned int* __restrict__ lists, unsigned short* __restrict__ kb2) {
  const int bt = blockIdx.x & 63;
  const int sub = blockIdx.x >> 6;          // 0..31
  unsigned int cnt = counts[bt];
  if (cnt > TILE_CAP) cnt = TILE_CAP;
  const unsigned int* mylist = lists + (size_t)bt * TILE_CAP;
  const int lane = threadIdx.x & 63;
  const int wib = threadIdx.x >> 6;         // wave in block 0..3
  const int g = lane >> 4;                  // flag group 0..3
  const int l16 = lane & 15;
  for (unsigned int i = (unsigned int)((sub * 4 + wib) * 4 + g); i < cnt; i += 512) {
    const unsigned int code = mylist[i];
    const int b = code >> 11, a = code & 2047;
    const float4* xp = reinterpret_cast<const float4*>(x + (size_t)b * D_DIM) + l16;
    const float4* ap = reinterpret_cast<const float4*>(anc + (size_t)a * D_DIM) + l16;
    double part[4] = {0.0, 0.0, 0.0, 0.0};
#pragma unroll
    for (int q = 0; q < 16; ++q) {
      const float4 xv = xp[16 * q];
      const float4 av = ap[16 * q];
      part[q & 3] += (double)xv.x * (double)av.x + (double)xv.y * (double)av.y +
                     (double)xv.z * (double)av.z + (double)xv.w * (double)av.w;
    }
    double s = (part[0] + part[1]) + (part[2] + part[3]);
    s += __shfl_xor(s, 8);
    s += __shfl_xor(s, 4);
    s += __shfl_xor(s, 2);
    s += __shfl_xor(s, 1);
    if (l16 == 0) {
      const double sim = s * inv_norms[b] * inv_norms[B_ROWS + a];
      const double kr = sim / 0.05;
      const double r = rint(kr);
      const double fr = kr - r;
      int k2 = 2 * (int)r;
      if (0.5 - fabs(fr) < 2.5e-6) k2 += (fr > 0.0) ? 1 : -1;  // midpoint hedge
      kb2[(size_t)b * A_ROWS + a] = bf16_rne((float)k2);       // exact int
    }
  }
}

// ---- GEMM2: bf16 chain, K=2048, 256^2 8-phase core, out = .025*k2@vbT -----
__global__ __launch_bounds__(512, 2) void gemm2_k(
    const unsigned short* __restrict__ kb2, const unsigned short* __restrict__ vbT,
    float* __restrict__ out) {
  __shared__ __align__(16) unsigned short smem[65536];  // 128 KB

  const int tid = threadIdx.x, lane = tid & 63, w = tid >> 6;
  const int wr = w >> 2, wc = w & 3;
  const int cl = lane & 15, kg = lane >> 4;
  // XCD-bijective swizzle (nwg=256, q=32)
  const int orig = blockIdx.y * 4 + blockIdx.x;
  const int swz = (orig & 7) * 32 + (orig >> 3);
  const int m0 = (swz >> 2) * 256, h0 = (swz & 3) * 256;

  f32x4 acc[8][4];
#pragma unroll
  for (int m = 0; m < 8; ++m)
#pragma unroll
    for (int n = 0; n < 4; ++n)
#pragma unroll
      for (int q = 0; q < 4; ++q) acc[m][n][q] = 0.0f;

  gemm_core<A_ROWS, false>(kb2, m0, vbT, h0, smem, acc, tid);

#pragma unroll
  for (int mi = 0; mi < 8; ++mi)
#pragma unroll
    for (int ni = 0; ni < 4; ++ni) {
      const int rowb = (mi >> 2) * 128 + wr * 64 + (mi & 3) * 16 + kg * 4;
      const int col = (ni >> 1) * 128 + wc * 32 + (ni & 1) * 16 + cl;
#pragma unroll
      for (int reg = 0; reg < 4; ++reg)
        out[(size_t)(m0 + rowb + reg) * H_DIM + h0 + col] =
            0.025f * acc[mi][ni][reg];
    }
}

// ---------------------------------------------------------------------------
extern "C" void kernel_launch(void* const* d_in, const int* in_sizes, int n_in,
                              void* d_out, int out_size, void* d_ws, size_t ws_size,
                              hipStream_t stream) {
  const float* x      = (const float*)d_in[0];
  const float* anc    = (const float*)d_in[1];
  const float* values = (const float*)d_in[2];
  float* out = (float*)d_out;

  char* ws = (char*)d_ws;
  double* inv_norms    = (double*)(ws);
  unsigned int* counts = (unsigned int*)(ws + 0x24000);
  unsigned int* lists  = (unsigned int*)(ws + 0x24200);
  unsigned short* xh   = (unsigned short*)(ws + 0x324000);
  unsigned short* ah   = (unsigned short*)(ws + 0x2324000);
  unsigned short* vbT  = (unsigned short*)(ws + 0x2724000);
  unsigned short* kb2  = (unsigned short*)(ws + 0x2B24000);

  normprep_k<<<B_ROWS, 256, 0, stream>>>(x, inv_norms, xh);
  normprep_k<<<A_ROWS, 256, 0, stream>>>(anc, inv_norms + B_ROWS, ah);
  prep_vt_k<<<dim3(H_DIM / 16, A_ROWS / 16), dim3(16, 16), 0, stream>>>(values, vbT, counts);
  gemm1_k<<<dim3(A_ROWS / 256, B_ROWS / 256), 512, 0, stream>>>(xh, ah, kb2, counts, lists);
  fixup_k<<<2048, 256, 0, stream>>>(x, anc, inv_norms, counts, lists, kb2);
  gemm2_k<<<dim3(H_DIM / 256, B_ROWS / 256), 512, 0, stream>>>(kb2, vbT, out);
}

// Round 4
// 289.665 us; speedup vs baseline: 1.1538x; 1.0201x over previous
//
#include <hip/hip_runtime.h>
#include <math.h>

// RelativeAttention: out = round((x_n @ a_n^T)/0.05)*0.05 @ values
//
// Round 21 (fix of r20 FAIL absmax 0.26): same read-ahead 8-phase schedule,
// with the ph4/ph8/tail-ph4 data-flow bug fixed: MM4(1,1) now executes
// BEFORE the next-tile RX/RB (r20 issued RX into Xf first, so the MFMA
// consumed the NEW undrained SSA values instead of X1 -> quadrant (1,1)
// garbage on odd tiles). Post-MM reads are the same SSA-safe pattern as
// ph2/ph6. Also: LDS bases via proper addrspace(3) cast (not flat-addr
// truncation) and smem __align__(128) so the ^64 ki-chunk XOR is exact.
//  - schedule: every operand read >=1 phase ahead of its MFMA; drains hide
//    under the previous MM's pipeline. Waits: LG0SB per phase (cheap, mostly
//    drained), vmcnt(6) at ph4/ph8 only. 10 barriers/group.
//  - frag reads: inline-asm ds_read_b128 off 8 precomputed byte bases ->
//    per-phase address VALU ~0.
//  - MFMA per-accumulator K-order unchanged -> bit-identical numerics
//    (absmax canary 2.685547e-3).
//
// ws layout (bytes):
//   [0x0,       0x24000)   inv_norms f64 (16384 x | 2048 anchors)
//   [0x24000,   0x24200)   counts u32[64] (128 slots reserved)
//   [0x24200,   0x224200)  lists u32[64][8192]
//   [0x324000,  0x2324000) xh f16 [16384][1024] (32MB)
//   [0x2324000, 0x2724000) ah f16 [2048][1024] (4MB)
//   [0x2724000, 0x2B24000) vbT bf16 [1024][2048] (values^T, 4MB)
//   [0x2B24000, 0x6B24000) kb2 bf16 [16384][2048] (2*bin, odd = midpoint)

#define B_ROWS 16384
#define A_ROWS 2048
#define D_DIM  1024
#define H_DIM  1024
#define TILE_CAP 8192u
#define LCAP 2040u

typedef __attribute__((ext_vector_type(8))) short short8;
typedef __attribute__((ext_vector_type(8))) _Float16 half8;
typedef __attribute__((ext_vector_type(4))) float f32x4;
typedef int v4i __attribute__((ext_vector_type(4)));

__device__ inline unsigned short bf16_rne(float f) {
  unsigned int u = __float_as_uint(f);
  unsigned int r = (u + 0x7FFFu + ((u >> 16) & 1u)) >> 16;
  return (unsigned short)r;
}
__device__ inline unsigned short f16_bits(float f) {
  _Float16 h = (_Float16)f;
  return __builtin_bit_cast(unsigned short, h);
}
__device__ inline void gload16(const void* g, void* l) {
  __builtin_amdgcn_global_load_lds(
      (const __attribute__((address_space(1))) unsigned int*)g,
      (__attribute__((address_space(3))) unsigned int*)l, 16, 0, 0);
}
__device__ inline int lds_off(const void* p) {
  return (int)(size_t)(const __attribute__((address_space(3))) void*)p;
}

template <bool F16>
__device__ __forceinline__ f32x4 mm16(v4i a, v4i b, f32x4 c) {
  if constexpr (F16)
    return __builtin_amdgcn_mfma_f32_16x16x32_f16(
        __builtin_bit_cast(half8, a), __builtin_bit_cast(half8, b), c, 0, 0, 0);
  else
    return __builtin_amdgcn_mfma_f32_16x16x32_bf16(
        __builtin_bit_cast(short8, a), __builtin_bit_cast(short8, b), c, 0, 0, 0);
}

// ------------- fused: norm (f64, r3-proven tree) + f16 convert -------------
__global__ __launch_bounds__(256) void normprep_k(
    const float* __restrict__ src, double* __restrict__ inv_out,
    unsigned short* __restrict__ dst) {
#pragma clang fp contract(off)
  const int r = blockIdx.x;
  const int t = threadIdx.x;
  const float4 v = reinterpret_cast<const float4*>(src + (size_t)r * D_DIM)[t];
  double s = (double)v.x * (double)v.x + (double)v.y * (double)v.y +
             (double)v.z * (double)v.z + (double)v.w * (double)v.w;
#pragma unroll
  for (int off = 32; off > 0; off >>= 1) s += __shfl_down(s, off);
  __shared__ double red[4];
  __shared__ double sinv;
  if ((t & 63) == 0) red[t >> 6] = s;
  __syncthreads();
  if (t == 0) {
    const double n = sqrt(red[0] + red[1] + red[2] + red[3]);
    const double inv = 1.0 / fmax(n, 1e-12);
    inv_out[r] = inv;
    sinv = inv;
  }
  __syncthreads();
  const float invn = (float)sinv;
  ushort4 o;
  o.x = f16_bits(v.x * invn); o.y = f16_bits(v.y * invn);
  o.z = f16_bits(v.z * invn); o.w = f16_bits(v.w * invn);
  reinterpret_cast<ushort4*>(dst + (size_t)r * D_DIM)[t] = o;
}

// ---------------------- prep: values^T as bf16 (+ zero counts) -------------
__global__ void prep_vt_k(const float* __restrict__ values,
                          unsigned short* __restrict__ vbT,
                          unsigned int* __restrict__ counts) {
  __shared__ float s[16][17];
  const int tx = threadIdx.x, ty = threadIdx.y;
  if (blockIdx.x == 0 && blockIdx.y == 0) {
    const int ft = ty * 16 + tx;
    if (ft < 128) counts[ft] = 0;
  }
  const int h0 = blockIdx.x * 16, a0 = blockIdx.y * 16;
  s[ty][tx] = values[(size_t)(a0 + ty) * H_DIM + h0 + tx];
  __syncthreads();
  vbT[(size_t)(h0 + ty) * A_ROWS + a0 + tx] = bf16_rne(s[tx][ty]);
}

// ------ 256x256 / BK=64 / 8-wave / 8-phase read-ahead GEMM core -----------
// LDS: buf0 {A:[256][64] @0, B @16384}, buf1 {A @32768, B @49152} (shorts).
// Chunk-XOR swizzle: row r's chunk k (16B) lives at slot k^(r&7); staging
// pre-swizzles the per-lane GLOBAL source so the LDS dest stays linear.
#define GBAR() __builtin_amdgcn_s_barrier()
#define LG0SB() do { asm volatile("s_waitcnt lgkmcnt(0)" ::: "memory"); \
                     __builtin_amdgcn_sched_barrier(0); } while (0)
#define SB0() __builtin_amdgcn_sched_barrier(0)
#define GVMC(n) asm volatile("s_waitcnt vmcnt(" #n ")" ::: "memory")

// ds_read_b128 with precomputed base VGPR + compile-time byte offset
#define DSR(d, b, i) \
  asm volatile("ds_read_b128 %0, %1 offset:%2" : "=v"(d) : "v"(b), "i"(i))

#define RX(b0, b1, mh) do { \
    DSR(Xf[0][0], b0, (mh)*16384 + 0);    DSR(Xf[0][1], b0, (mh)*16384 + 2048); \
    DSR(Xf[0][2], b0, (mh)*16384 + 4096); DSR(Xf[0][3], b0, (mh)*16384 + 6144); \
    DSR(Xf[1][0], b1, (mh)*16384 + 0);    DSR(Xf[1][1], b1, (mh)*16384 + 2048); \
    DSR(Xf[1][2], b1, (mh)*16384 + 4096); DSR(Xf[1][3], b1, (mh)*16384 + 6144); \
  } while (0)

#define RB(b0, b1, nh) do { \
    DSR(Bf[nh][0][0], b0, (nh)*16384 + 0); DSR(Bf[nh][0][1], b0, (nh)*16384 + 2048); \
    DSR(Bf[nh][1][0], b1, (nh)*16384 + 0); DSR(Bf[nh][1][1], b1, (nh)*16384 + 2048); \
  } while (0)

#define SCA(buf, c, kv) gload16(aS + (size_t)(c) * 64 * KDIM + (kv), \
                                (buf) + (c) * 4096 + tid * 8)
#define SCB(buf, c, kv) gload16(bS + (size_t)(c) * 64 * KDIM + (kv), \
                                (buf) + (c) * 4096 + tid * 8)

#define MM4(mh, nh) do { \
    __builtin_amdgcn_s_setprio(1); \
    _Pragma("unroll") for (int ki_ = 0; ki_ < 2; ++ki_) \
    _Pragma("unroll") for (int m_ = 0; m_ < 4; ++m_) \
    _Pragma("unroll") for (int n_ = 0; n_ < 2; ++n_) \
      acc[(mh) * 4 + m_][(nh) * 2 + n_] = mm16<F16>( \
          Xf[ki_][m_], Bf[nh][ki_][n_], acc[(mh) * 4 + m_][(nh) * 2 + n_]); \
    __builtin_amdgcn_s_setprio(0); \
  } while (0)

template <int KDIM, bool F16>
__device__ __forceinline__ void gemm_core(
    const unsigned short* __restrict__ Amat, int m0,
    const unsigned short* __restrict__ Bmat, int n0,
    unsigned short* smem, f32x4 (&acc)[8][4], const int tid) {
  static_assert(KDIM % 128 == 0 && KDIM >= 256, "KDIM");
  const int lane = tid & 63, w = tid >> 6;
  const int wr = w >> 2, wc = w & 3;
  const int cl = lane & 15, kg = lane >> 4;
  unsigned short* const A0b = smem;
  unsigned short* const B0b = smem + 16384;
  unsigned short* const A1b = smem + 32768;
  unsigned short* const B1b = smem + 49152;
  // staging geometry: call c covers rows c*64 + (tid>>3), chunk slot tid&7;
  // source chunk = slot ^ (row&7); (c*64)&7==0 so the XOR is c-invariant.
  const int srow = tid >> 3;
  const int tcs = (tid & 7) ^ (srow & 7);
  const unsigned short* aS = Amat + (size_t)(m0 + srow) * KDIM + tcs * 8;
  const unsigned short* bS = Bmat + (size_t)(n0 + srow) * KDIM + tcs * 8;

  // precomputed per-wave LDS byte bases (buf x ki), frag-read swizzle baked in
  const int smb = lds_off(smem);
  const int cb = (kg ^ (cl & 7)) * 16;
  const int baA00 = smb + wr * 8192 + cl * 128 + cb;
  const int baA01 = baA00 ^ 64;
  const int baA10 = baA00 + 65536, baA11 = baA01 + 65536;
  const int baB00 = smb + 32768 + wc * 4096 + cl * 128 + cb;
  const int baB01 = baB00 ^ 64;
  const int baB10 = baB00 + 65536, baB11 = baB01 + 65536;

  v4i Xf[2][4], Bf[2][2][2];

  // prologue: t0 full (8) + t1 sans A-h1 (6) = 14 loads; wait all but t1's 6
  SCA(A0b, 0, 0); SCA(A0b, 1, 0);
  SCB(B0b, 0, 0); SCB(B0b, 1, 0);
  SCB(B0b, 2, 0); SCB(B0b, 3, 0);
  SCA(A0b, 2, 0); SCA(A0b, 3, 0);
  SCA(A1b, 0, 64); SCA(A1b, 1, 64);
  SCB(B1b, 0, 64); SCB(B1b, 1, 64);
  SCB(B1b, 2, 64); SCB(B1b, 3, 64);
  GVMC(6);
  GBAR();
  RX(baA00, baA01, 0);  // X0(t0)
  RB(baB00, baB01, 0);  // B0(t0)

  constexpr int G = KDIM / 128;  // groups of 2 K-tiles
#pragma unroll 1
  for (int g = 0; g < G - 1; ++g) {
    const int kA = g * 128 + 64;   // t1 = 2g+1 (buf1): A-h1 staged ph1
    const int kB = g * 128 + 128;  // t2 = 2g+2 (buf0): staged ph2-5
    const int kC = g * 128 + 192;  // t3 = 2g+3 (buf1): 3 halves, ph6-8
    // ph1: MM(0,0)=X0*B0; read B1 (for ph2)
    SCA(A1b, 2, kA); SCA(A1b, 3, kA);
    LG0SB();                       // X0,B0 drained (issued prev ph8)
    RB(baB00, baB01, 1);
    SB0();
    MM4(0, 0);
    GBAR();
    // ph2: MM(0,1)=X0*B1; post-MM read X1 (SSA: MM reads old Xf)
    SCA(A0b, 0, kB); SCA(A0b, 1, kB);
    LG0SB();                       // B1 drained under MM1
    MM4(0, 1);
    RX(baA00, baA01, 1);
    GBAR();
    // ph3: MM(1,0)=X1*B0
    SCB(B0b, 0, kB); SCB(B0b, 1, kB);
    LG0SB();                       // X1 (short exposure)
    MM4(1, 0);
    GBAR();
    // ph4: MM(1,1)=X1*B1 FIRST (operands already drained); then vmc6+BAR
    // (t1 resident all-waves); then read X0',B0' (drain at ph5 LG0SB).
    SCB(B0b, 2, kB); SCB(B0b, 3, kB);
    MM4(1, 1);
    GVMC(6);
    GBAR();
    RX(baA10, baA11, 0);
    RB(baB10, baB11, 0);
    GBAR();
    // ph5: MM(0,0)'=X0'*B0'; read B1'
    SCA(A0b, 2, kB); SCA(A0b, 3, kB);
    LG0SB();                       // X0',B0' drained under MM4's pipe
    RB(baB10, baB11, 1);
    SB0();
    MM4(0, 0);
    GBAR();
    // ph6: MM(0,1)'=X0'*B1'; post-MM read X1'
    SCA(A1b, 0, kC); SCA(A1b, 1, kC);
    LG0SB();                       // B1' drained under MM5
    MM4(0, 1);
    RX(baA10, baA11, 1);
    GBAR();
    // ph7: MM(1,0)'=X1'*B0'
    SCB(B1b, 0, kC); SCB(B1b, 1, kC);
    LG0SB();                       // X1' (short exposure)
    MM4(1, 0);
    GBAR();
    // ph8: MM(1,1)'=X1'*B1' FIRST; vmc6+BAR (t2 resident); read X0'',B0''
    SCB(B1b, 2, kC); SCB(B1b, 3, kC);
    MM4(1, 1);
    GVMC(6);
    GBAR();
    RX(baA00, baA01, 0);
    RB(baB00, baB01, 0);
    GBAR();
  }
  // tail group: t_{2G-2}(buf0), t_{2G-1}(buf1); only t_{2G-1} A-h1 to stage
  {
    const int kA = KDIM - 64;
    SCA(A1b, 2, kA); SCA(A1b, 3, kA);
    LG0SB(); RB(baB00, baB01, 1); SB0(); MM4(0, 0); GBAR();
    LG0SB(); MM4(0, 1); RX(baA00, baA01, 1); GBAR();
    LG0SB(); MM4(1, 0); GBAR();
    MM4(1, 1);
    GVMC(0);
    GBAR();
    RX(baA10, baA11, 0);
    RB(baB10, baB11, 0);
    GBAR();
    LG0SB(); RB(baB10, baB11, 1); SB0(); MM4(0, 0); GBAR();
    LG0SB(); MM4(0, 1); RX(baA10, baA11, 1); GBAR();
    LG0SB(); MM4(1, 0); GBAR();
    LG0SB(); MM4(1, 1);
  }
}

// ---- GEMM1: f16 chain, 256^2 8-phase core + quantize/flag/flush epilogue --
__global__ __launch_bounds__(512, 2) void gemm1_k(
    const unsigned short* __restrict__ xh, const unsigned short* __restrict__ ah,
    unsigned short* __restrict__ kb2, unsigned int* __restrict__ counts,
    unsigned int* __restrict__ lists) {
  __shared__ __align__(128) unsigned short smem[65536];  // 128 KB
  __shared__ unsigned int lmeta[2050];

  const int tid = threadIdx.x, lane = tid & 63, w = tid >> 6;
  const int wr = w >> 2, wc = w & 3;
  const int cl = lane & 15, kg = lane >> 4;
  // XCD-bijective swizzle (m204; nwg=512, nwg%8==0, q=64)
  const int orig = blockIdx.y * 8 + blockIdx.x;
  const int swz = (orig & 7) * 64 + (orig >> 3);
  const int m0 = (swz >> 3) * 256, n0 = (swz & 7) * 256;
  const int bt = m0 >> 8;  // 256-row slab index 0..63

  f32x4 acc[8][4];
#pragma unroll
  for (int m = 0; m < 8; ++m)
#pragma unroll
    for (int n = 0; n < 4; ++n)
#pragma unroll
      for (int q = 0; q < 4; ++q) acc[m][n][q] = 0.0f;

  if (tid == 0) lmeta[0] = 0;  // published by core's prologue barrier

  gemm_core<D_DIM, true>(xh, m0, ah, n0, smem, acc, tid);

  // ---- epilogue: quantize -> bf16 2k in LDS (XOR-swz), flags, flush ------
  __syncthreads();
  unsigned short* sq = smem;  // [256][256] bf16, chunk-swizzled
  unsigned int* mylist = lists + (size_t)bt * TILE_CAP;
#pragma unroll
  for (int mi = 0; mi < 8; ++mi)
#pragma unroll
    for (int ni = 0; ni < 4; ++ni) {
      const int rowb = (mi >> 2) * 128 + wr * 64 + (mi & 3) * 16 + kg * 4;
      const int col = (ni >> 1) * 128 + wc * 32 + (ni & 1) * 16 + cl;
#pragma unroll
      for (int reg = 0; reg < 4; ++reg) {
        const int row = rowb + reg;
        const float kr = acc[mi][ni][reg] * 20.0f;
        const float rr = rintf(kr);
        if (0.5f - fabsf(kr - rr) < 2e-3f) {  // r7-r19-validated window
          const unsigned int code =
              ((unsigned int)(m0 + row) << 11) | (unsigned int)(n0 + col);
          const unsigned int li = atomicAdd(&lmeta[0], 1u);  // LDS atomic
          if (li < LCAP) lmeta[1 + li] = code;
          else {
            const unsigned int gi = atomicAdd(&counts[bt], 1u);
            if (gi < TILE_CAP) mylist[gi] = code;
          }
        }
        // swizzled store: chunk (col>>3) with low 3 bits XOR (row&7)
        const int ch = col >> 3;
        const int csw = (ch & 24) | ((ch & 7) ^ (row & 7));
        sq[row * 256 + csw * 8 + (col & 7)] =
            bf16_rne((float)(2 * (int)rr));  // exact
      }
    }
  __syncthreads();
  if (tid == 0) {
    const unsigned int c = lmeta[0] < LCAP ? lmeta[0] : LCAP;
    lmeta[2049] = atomicAdd(&counts[bt], c);  // ONE global atomic per block
  }
  __syncthreads();
  {
    const unsigned int c = lmeta[0] < LCAP ? lmeta[0] : LCAP;
    const unsigned int base = lmeta[2049];
    for (unsigned int t = tid; t < c; t += 512)
      if (base + t < TILE_CAP) mylist[base + t] = lmeta[1 + t];
  }
  {
    const int row = tid >> 1, half = tid & 1;
    unsigned short* dst = kb2 + (size_t)(m0 + row) * A_ROWS + n0 + half * 128;
#pragma unroll
    for (int j = 0; j < 16; ++j) {
      const int creal = half * 16 + j;
      const int csw = (creal & 24) | ((creal & 7) ^ (row & 7));
      reinterpret_cast<int4*>(dst)[j] =
          *reinterpret_cast<const int4*>(sq + row * 256 + csw * 8);
    }
  }
}

// ---- fixup: 4 flags/wave (16-lane groups), bucketed, XCD-co-located -------
__global__ __launch_bounds__(256) void fixup_k(
    const float* __restrict__ x, const float* __restrict__ anc,
    const double* __restrict__ inv_norms, const unsigned int* __restrict__ counts,
    const unsigned int* __restrict__ lists, unsigned short* __restrict__ kb2) {
  const int bt = blockIdx.x & 63;
  const int sub = blockIdx.x >> 6;          // 0..31
  unsigned int cnt = counts[bt];
  if (cnt > TILE_CAP) cnt = TILE_CAP;
  const unsigned int* mylist = lists + (size_t)bt * TILE_CAP;
  const int lane = threadIdx.x & 63;
  const int wib = threadIdx.x >> 6;         // wave in block 0..3
  const int g = lane >> 4;                  // flag group 0..3
  const int l16 = lane & 15;
  for (unsigned int i = (unsigned int)((sub * 4 + wib) * 4 + g); i < cnt; i += 512) {
    const unsigned int code = mylist[i];
    const int b = code >> 11, a = code & 2047;
    const float4* xp = reinterpret_cast<const float4*>(x + (size_t)b * D_DIM) + l16;
    const float4* ap = reinterpret_cast<const float4*>(anc + (size_t)a * D_DIM) + l16;
    double part[4] = {0.0, 0.0, 0.0, 0.0};
#pragma unroll
    for (int q = 0; q < 16; ++q) {
      const float4 xv = xp[16 * q];
      const float4 av = ap[16 * q];
      part[q & 3] += (double)xv.x * (double)av.x + (double)xv.y * (double)av.y +
                     (double)xv.z * (double)av.z + (double)xv.w * (double)av.w;
    }
    double s = (part[0] + part[1]) + (part[2] + part[3]);
    s += __shfl_xor(s, 8);
    s += __shfl_xor(s, 4);
    s += __shfl_xor(s, 2);
    s += __shfl_xor(s, 1);
    if (l16 == 0) {
      const double sim = s * inv_norms[b] * inv_norms[B_ROWS + a];
      const double kr = sim / 0.05;
      const double r = rint(kr);
      const double fr = kr - r;
      int k2 = 2 * (int)r;
      if (0.5 - fabs(fr) < 2.5e-6) k2 += (fr > 0.0) ? 1 : -1;  // midpoint hedge
      kb2[(size_t)b * A_ROWS + a] = bf16_rne((float)k2);       // exact int
    }
  }
}

// ---- GEMM2: bf16 chain, K=2048, 256^2 8-phase core, out = .025*k2@vbT -----
__global__ __launch_bounds__(512, 2) void gemm2_k(
    const unsigned short* __restrict__ kb2, const unsigned short* __restrict__ vbT,
    float* __restrict__ out) {
  __shared__ __align__(128) unsigned short smem[65536];  // 128 KB

  const int tid = threadIdx.x, lane = tid & 63, w = tid >> 6;
  const int wr = w >> 2, wc = w & 3;
  const int cl = lane & 15, kg = lane >> 4;
  // XCD-bijective swizzle (nwg=256, q=32)
  const int orig = blockIdx.y * 4 + blockIdx.x;
  const int swz = (orig & 7) * 32 + (orig >> 3);
  const int m0 = (swz >> 2) * 256, h0 = (swz & 3) * 256;

  f32x4 acc[8][4];
#pragma unroll
  for (int m = 0; m < 8; ++m)
#pragma unroll
    for (int n = 0; n < 4; ++n)
#pragma unroll
      for (int q = 0; q < 4; ++q) acc[m][n][q] = 0.0f;

  gemm_core<A_ROWS, false>(kb2, m0, vbT, h0, smem, acc, tid);

#pragma unroll
  for (int mi = 0; mi < 8; ++mi)
#pragma unroll
    for (int ni = 0; ni < 4; ++ni) {
      const int rowb = (mi >> 2) * 128 + wr * 64 + (mi & 3) * 16 + kg * 4;
      const int col = (ni >> 1) * 128 + wc * 32 + (ni & 1) * 16 + cl;
#pragma unroll
      for (int reg = 0; reg < 4; ++reg)
        out[(size_t)(m0 + rowb + reg) * H_DIM + h0 + col] =
            0.025f * acc[mi][ni][reg];
    }
}

// ---------------------------------------------------------------------------
extern "C" void kernel_launch(void* const* d_in, const int* in_sizes, int n_in,
                              void* d_out, int out_size, void* d_ws, size_t ws_size,
                              hipStream_t stream) {
  const float* x      = (const float*)d_in[0];
  const float* anc    = (const float*)d_in[1];
  const float* values = (const float*)d_in[2];
  float* out = (float*)d_out;

  char* ws = (char*)d_ws;
  double* inv_norms    = (double*)(ws);
  unsigned int* counts = (unsigned int*)(ws + 0x24000);
  unsigned int* lists  = (unsigned int*)(ws + 0x24200);
  unsigned short* xh   = (unsigned short*)(ws + 0x324000);
  unsigned short* ah   = (unsigned short*)(ws + 0x2324000);
  unsigned short* vbT  = (unsigned short*)(ws + 0x2724000);
  unsigned short* kb2  = (unsigned short*)(ws + 0x2B24000);

  normprep_k<<<B_ROWS, 256, 0, stream>>>(x, inv_norms, xh);
  normprep_k<<<A_ROWS, 256, 0, stream>>>(anc, inv_norms + B_ROWS, ah);
  prep_vt_k<<<dim3(H_DIM / 16, A_ROWS / 16), dim3(16, 16), 0, stream>>>(values, vbT, counts);
  gemm1_k<<<dim3(A_ROWS / 256, B_ROWS / 256), 512, 0, stream>>>(xh, ah, kb2, counts, lists);
  fixup_k<<<2048, 256, 0, stream>>>(x, anc, inv_norms, counts, lists, kb2);
  gemm2_k<<<dim3(H_DIM / 256, B_ROWS / 256), 512, 0, stream>>>(kb2, vbT, out);
}